// Round 1
// baseline (73.851 us; speedup 1.0000x reference)
//
#include <hip/hip_runtime.h>

#define L_TOTAL 32768
#define D_MODEL 1024
#define CHUNK   128                      // l's per block in signal kernel
#define BLOCKS_A (L_TOTAL / CHUNK)       // 256 blocks -> 1024 waves, 4/CU

// Stage 1: signal[d] = sum_l sin(2*pi * x[l] * (t[d] + log1p(l)))
// Phase computed in revolutions: sin_hw(fract(x*t + x*p)).
// Each thread owns d = tid + 256*j (j=0..3). Block handles CHUNK l's.
__global__ __launch_bounds__(256) void signal_kernel(const float* __restrict__ x,
                                                     float* __restrict__ signal) {
    __shared__ float xs[CHUNK];
    __shared__ float ps[CHUNK];
    const int tid  = threadIdx.x;
    const int base = blockIdx.x * CHUNK;
    if (tid < CHUNK) {
        xs[tid] = x[base + tid];
        ps[tid] = __logf(1.0f + (float)(base + tid));   // log1p(l), l+1 exact in f32
    }
    __syncthreads();

    const float inv = 1.0f / 1023.0f;                   // linspace(0,1,1024) step
    const float t0 = (float)(tid)        * inv;
    const float t1 = (float)(tid + 256)  * inv;
    const float t2 = (float)(tid + 512)  * inv;
    const float t3 = (float)(tid + 768)  * inv;

    float a0 = 0.f, a1 = 0.f, a2 = 0.f, a3 = 0.f;
    #pragma unroll 8
    for (int il = 0; il < CHUNK; ++il) {
        const float xv = xs[il];        // uniform LDS read -> broadcast, no conflict
        const float ap = xv * ps[il];   // x*p term (revolutions)
        const float g0 = __builtin_amdgcn_fractf(fmaf(xv, t0, ap));
        const float g1 = __builtin_amdgcn_fractf(fmaf(xv, t1, ap));
        const float g2 = __builtin_amdgcn_fractf(fmaf(xv, t2, ap));
        const float g3 = __builtin_amdgcn_fractf(fmaf(xv, t3, ap));
        a0 += __builtin_amdgcn_sinf(g0);  // v_sin_f32: sin(2*pi*arg), arg in [0,1)
        a1 += __builtin_amdgcn_sinf(g1);
        a2 += __builtin_amdgcn_sinf(g2);
        a3 += __builtin_amdgcn_sinf(g3);
    }
    atomicAdd(&signal[tid],        a0);
    atomicAdd(&signal[tid + 256],  a1);
    atomicAdd(&signal[tid + 512],  a2);
    atomicAdd(&signal[tid + 768],  a3);
}

// Stage 2: out[r] = b[r] + dot(signal, W[r, :])   (x @ W.T)
// One 64-lane wave per row; float4 loads, shuffle reduce.
__global__ __launch_bounds__(256) void matvec_kernel(const float* __restrict__ W,
                                                     const float* __restrict__ b,
                                                     const float* __restrict__ signal,
                                                     float* __restrict__ out) {
    const int wave = threadIdx.x >> 6;
    const int lane = threadIdx.x & 63;
    const int row  = blockIdx.x * 4 + wave;

    const float4* Wr = (const float4*)(W + (size_t)row * D_MODEL);
    const float4* S  = (const float4*)signal;

    float sum = 0.f;
    #pragma unroll
    for (int k = 0; k < 4; ++k) {
        const float4 w4 = Wr[lane + 64 * k];
        const float4 s4 = S[lane + 64 * k];
        sum += w4.x * s4.x + w4.y * s4.y + w4.z * s4.z + w4.w * s4.w;
    }
    #pragma unroll
    for (int off = 32; off > 0; off >>= 1)
        sum += __shfl_down(sum, off, 64);
    if (lane == 0) out[row] = sum + b[row];
}

extern "C" void kernel_launch(void* const* d_in, const int* in_sizes, int n_in,
                              void* d_out, int out_size, void* d_ws, size_t ws_size,
                              hipStream_t stream) {
    const float* x = (const float*)d_in[0];   // inputs [32768]
    const float* W = (const float*)d_in[1];   // W [1024,1024]
    const float* b = (const float*)d_in[2];   // b [1024]
    float* out    = (float*)d_out;            // [1024] f32
    float* signal = (float*)d_ws;             // 4 KB accumulator in workspace

    hipMemsetAsync(signal, 0, D_MODEL * sizeof(float), stream);
    signal_kernel<<<BLOCKS_A, 256, 0, stream>>>(x, signal);
    matvec_kernel<<<D_MODEL / 4, 256, 0, stream>>>(W, b, signal, out);
}

// Round 2
// 73.056 us; speedup vs baseline: 1.0109x; 1.0109x over previous
//
#include <hip/hip_runtime.h>

#define L_TOTAL 32768
#define D_MODEL 1024
#define CHUNK   128                      // l's per block in signal kernel
#define BLOCKS_A (L_TOTAL / CHUNK)       // 256 blocks x 1024 thr -> 16 waves/CU

// Stage 1: signal[d] = sum_l sin(2*pi * x[l] * (t[d] + log1p(l)))
// Phase in revolutions: v_sin_f32(fract(x*t + x*p)).
// One thread per d (1024 thr/block); block handles CHUNK l's.
// LDS holds {x[l], x[l]*log1p(l)} so the inner loop is fma+fract+sin+add.
__global__ __launch_bounds__(1024) void signal_kernel(const float* __restrict__ x,
                                                      float* __restrict__ signal) {
    __shared__ float2 sxp[CHUNK];
    const int tid  = threadIdx.x;
    const int base = blockIdx.x * CHUNK;
    if (tid < CHUNK) {
        const float xv = x[base + tid];
        const float pv = __logf(1.0f + (float)(base + tid));  // log1p(l), exact arg
        sxp[tid] = make_float2(xv, xv * pv);
    }
    __syncthreads();

    const float t = (float)tid * (1.0f / 1023.0f);  // linspace(0,1,1024)
    float a = 0.f;
    #pragma unroll 8
    for (int il = 0; il < CHUNK; ++il) {
        const float2 v = sxp[il];                    // wave-uniform broadcast b64
        const float g = __builtin_amdgcn_fractf(fmaf(v.x, t, v.y));
        a += __builtin_amdgcn_sinf(g);               // v_sin_f32: arg in revolutions
    }
    atomicAdd(&signal[tid], a);                      // 1 atomic per addr per block
}

// Stage 2: out[r] = b[r] + dot(signal, W[r, :])   (x @ W.T)
// One 64-lane wave per row; float4 loads, shuffle reduce.
__global__ __launch_bounds__(256) void matvec_kernel(const float* __restrict__ W,
                                                     const float* __restrict__ b,
                                                     const float* __restrict__ signal,
                                                     float* __restrict__ out) {
    const int wave = threadIdx.x >> 6;
    const int lane = threadIdx.x & 63;
    const int row  = blockIdx.x * 4 + wave;

    const float4* Wr = (const float4*)(W + (size_t)row * D_MODEL);
    const float4* S  = (const float4*)signal;

    float sum = 0.f;
    #pragma unroll
    for (int k = 0; k < 4; ++k) {
        const float4 w4 = Wr[lane + 64 * k];
        const float4 s4 = S[lane + 64 * k];
        sum += w4.x * s4.x + w4.y * s4.y + w4.z * s4.z + w4.w * s4.w;
    }
    #pragma unroll
    for (int off = 32; off > 0; off >>= 1)
        sum += __shfl_down(sum, off, 64);
    if (lane == 0) out[row] = sum + b[row];
}

extern "C" void kernel_launch(void* const* d_in, const int* in_sizes, int n_in,
                              void* d_out, int out_size, void* d_ws, size_t ws_size,
                              hipStream_t stream) {
    const float* x = (const float*)d_in[0];   // inputs [32768]
    const float* W = (const float*)d_in[1];   // W [1024,1024]
    const float* b = (const float*)d_in[2];   // b [1024]
    float* out    = (float*)d_out;            // [1024] f32
    float* signal = (float*)d_ws;             // 4 KB accumulator in workspace

    hipMemsetAsync(signal, 0, D_MODEL * sizeof(float), stream);
    signal_kernel<<<BLOCKS_A, 1024, 0, stream>>>(x, signal);
    matvec_kernel<<<D_MODEL / 4, 256, 0, stream>>>(W, b, signal, out);
}